// Round 20
// baseline (258.401 us; speedup 1.0000x reference)
//
#include <hip/hip_runtime.h>
#include <cstdint>
#include <cstddef>

#define S_LEN   2048
#define N_HEADS 8
#define N_BATCH 2
#define TOPK    409      // int(2048 * (1.0 - 0.8)) in python double arithmetic
#define HALF_WIN 32
#define KEY_P0  0x80000000u   // mono(+0.0f)
#define KEY_N0  0x7FFFFFFFu   // mono(-0.0f)  (total order: -0 < +0)
#define HIST_STRIDE 260       // words; wave w's hist row starts at bank 4w

__device__ __forceinline__ unsigned mbcnt64(unsigned long long m) {
  return __builtin_amdgcn_mbcnt_hi((unsigned)(m >> 32),
         __builtin_amdgcn_mbcnt_lo((unsigned)m, 0u));
}

__device__ __forceinline__ unsigned mono1(float f) {
  unsigned u = __float_as_uint(f);
  return (u & 0x80000000u) ? ~u : (u | 0x80000000u);
}

// MSD radix select over the positive (key>+0) or negative (key<-0) subset.
// Wave-scope (no barriers). Keys in a register array.
__device__ __forceinline__ void radix_range(const unsigned (&keys)[32], unsigned kk0,
                                            bool pos, unsigned* h, int l,
                                            unsigned& T_ret, unsigned& kk_ret,
                                            bool& cnt1) {
  unsigned prefix = 0, done = 0, kk = kk0;
  unsigned T = 0;
  bool resolved = false;
  cnt1 = false;
  #pragma unroll
  for (int pass = 0; pass < 4; ++pass) {
    const int shift = 24 - 8 * pass;
    *(uint4*)&h[l * 4] = make_uint4(0, 0, 0, 0);
    __threadfence_block();
    #pragma unroll
    for (int q = 0; q < 32; ++q) {
      unsigned kj = keys[q];
      bool in = pos ? (kj > KEY_P0) : (kj < KEY_N0);
      if (in && (kj & done) == prefix)
        atomicAdd(&h[(kj >> shift) & 255u], 1u);
    }
    __threadfence_block();
    uint4 hv = *(const uint4*)&h[l * 4];
    unsigned s3 = hv.w;
    unsigned s2 = hv.z + s3;
    unsigned s1 = hv.y + s2;
    unsigned s0 = hv.x + s1;
    unsigned inc = s0;
    #pragma unroll
    for (int d = 1; d < 64; d <<= 1) {
      unsigned o = __shfl_down(inc, d);
      inc += (l + d < 64) ? o : 0u;
    }
    const unsigned tail = inc - s0;
    const unsigned ge[4] = {s0 + tail, s1 + tail, s2 + tail, s3 + tail};
    const unsigned gt[4] = {s1 + tail, s2 + tail, s3 + tail, tail};
    unsigned packed = 0;
    bool found = false;
    #pragma unroll
    for (int q = 0; q < 4; ++q) {
      if (gt[q] < kk && kk <= ge[q]) {
        packed = ((unsigned)(4 * l + q) << 24) | ((ge[q] - gt[q]) << 12) | (kk - gt[q]);
        found = true;
      }
    }
    unsigned long long bal = __ballot(found);
    int srcl = __ffsll((long long)bal) - 1;
    packed = __shfl(packed, srcl);
    const unsigned cnt = (packed >> 12) & 0xFFFu;
    kk = packed & 0xFFFu;
    prefix |= (packed >> 24) << shift;
    done |= 0xFFu << shift;
    if (cnt == 1u) {
      unsigned cand = 0;
      #pragma unroll
      for (int q = 0; q < 32; ++q) {
        unsigned kj = keys[q];
        bool in = pos ? (kj > KEY_P0) : (kj < KEY_N0);
        if (in && (kj & done) == prefix) cand = kj;
      }
      #pragma unroll
      for (int d = 1; d < 64; d <<= 1) cand |= __shfl_xor(cand, d);
      T = cand;                              // kk == 1 here
      resolved = true;
      cnt1 = true;
      break;
    }
  }
  if (!resolved) T = prefix;
  T_ret = T;
  kk_ret = kk;
}

// Resolve threshold T + tie-take count kk for top-TOPK of 2048 keys (32/lane).
// Order: positives > +0 > -0 > negatives; n0/n1 counted lazily.
__device__ __forceinline__ void resolve_T(const unsigned (&keys)[32], unsigned* h,
                                          int l, unsigned& T, unsigned& kk,
                                          bool& cnt1) {
  unsigned np = 0;
  #pragma unroll
  for (int q = 0; q < 32; ++q)
    np += (unsigned)__popcll(__ballot(keys[q] > KEY_P0));
  if (TOPK <= np) {
    radix_range(keys, TOPK, true, h, l, T, kk, cnt1);
  } else {
    unsigned n0 = 0, n1 = 0;
    #pragma unroll
    for (int q = 0; q < 32; ++q) {
      unsigned kj = keys[q];
      n0 += (unsigned)__popcll(__ballot(kj == KEY_P0));
      n1 += (unsigned)__popcll(__ballot(kj == KEY_N0));
    }
    if (TOPK <= np + n0)           { T = KEY_P0; kk = TOPK - np;      cnt1 = (n0 == 1); }
    else if (TOPK <= np + n0 + n1) { T = KEY_N0; kk = TOPK - np - n0; cnt1 = (n1 == 1); }
    else radix_range(keys, TOPK - np - n0 - n1, false, h, l, T, kk, cnt1);
  }
}

// Per-lane selection bits (bit q=4s+e <-> column j=256s+4l+e). Stable
// lowest-index-first tie handling; ballot-free fast path when cnt1.
__device__ __forceinline__ unsigned select_bits(const unsigned (&keys)[32],
                                                unsigned T, unsigned kk,
                                                bool cnt1, int l) {
  unsigned bits = 0;
  if (cnt1) {
    #pragma unroll
    for (int q = 0; q < 32; ++q)
      bits |= (keys[q] >= T ? 1u : 0u) << q;
    return bits;
  }
  unsigned S_tot = 0;
  #pragma unroll
  for (int s = 0; s < 8; ++s) {
    unsigned long long beq[4];
    unsigned pe[4];
    #pragma unroll
    for (int e = 0; e < 4; ++e) {
      beq[e] = __ballot(keys[4 * s + e] == T);
      pe[e] = (unsigned)__popcll(beq[e]);
    }
    const unsigned th = pe[0] + pe[1] + pe[2] + pe[3];
    if (S_tot + th <= kk) {
      #pragma unroll
      for (int e = 0; e < 4; ++e)
        bits |= (keys[4 * s + e] >= T ? 1u : 0u) << (4 * s + e);
    } else if (S_tot >= kk) {
      #pragma unroll
      for (int e = 0; e < 4; ++e)
        bits |= (keys[4 * s + e] > T ? 1u : 0u) << (4 * s + e);
    } else {                                 // boundary block (exactly one)
      unsigned mb[4], own[4];
      #pragma unroll
      for (int e = 0; e < 4; ++e) {
        mb[e]  = mbcnt64(beq[e]);
        own[e] = (unsigned)((beq[e] >> l) & 1ull);
      }
      const unsigned cross = S_tot + mb[0] + mb[1] + mb[2] + mb[3];
      unsigned run = 0;
      #pragma unroll
      for (int e = 0; e < 4; ++e) {
        unsigned kj = keys[4 * s + e];
        bool sel = (kj > T) || (kj == T && (cross + run) < kk);
        run += own[e];
        bits |= (sel ? 1u : 0u) << (4 * s + e);
      }
    }
    S_tot += th;
  }
  return bits;
}

// Fused kernel: block = (b,i), 256 threads = 4 waves, 2 heads per wave.
// R19 + latency hiding at safe VGPR cap (256,4 -> 128): during P2, issue
// BOTH heads' rand loads (cold; overlap with the sum's loads for MLP) and
// head A's score row (L2-warm) -> P3b-A starts with operands in registers;
// only head B's score re-read remains exposed (L2-warm). R18 tried this at
// (256,6)/cap-85 and spilled; peak live state here ~100 VGPR < 128.
__global__ __launch_bounds__(256, 4) void k_fused(const float* __restrict__ scores,
                                                  const float* __restrict__ randu,
                                                  float* __restrict__ out) {
  __shared__ __align__(16) unsigned keyrow[S_LEN];         // 8 KB gmask keys
  __shared__ __align__(16) unsigned hist[4 * HIST_STRIDE]; // 4.2 KB
  __shared__ unsigned gq[64];                              // select words
  const int l = threadIdx.x & 63;          // lane
  const int w = threadIdx.x >> 6;          // wave 0..3
  const int bi = blockIdx.x;               // b * S + i
  const int b = bi >> 11;
  const int i = bi & 2047;
  const size_t gbase = (((size_t)(b * N_HEADS)) * S_LEN + i) * S_LEN; // head 0
  const float thr = (float)(1.0 - 0.8);    // 0x3E4CCCCD, JAX f32 demotion
  unsigned* const h = hist + (size_t)w * HIST_STRIDE;
  const size_t rowA = gbase + (size_t)(2 * w) * S_LEN * S_LEN;
  const size_t rowB = rowA + (size_t)S_LEN * S_LEN;

  // ---- P2: head-sum of own 512-col slice; rand prefetch for both heads;
  //      head A score row into regs (all loads overlap for MLP) ----
  unsigned rndA = 0, rndB = 0;
  unsigned sbA[32];
  #pragma unroll
  for (int t = 0; t < 2; ++t) {
    const int s = 2 * w + t;               // 256-col chunk index
    const int c0 = 256 * s + 4 * l;
    float4 p = *(const float4*)(scores + gbase + c0);
    #pragma unroll
    for (int hh = 1; hh < N_HEADS; ++hh) {  // sequential head order
      float4 x = *(const float4*)(scores + gbase + (size_t)hh * S_LEN * S_LEN + c0);
      p.x += x.x; p.y += x.y; p.z += x.z; p.w += x.w;
    }
    const float av[4] = {p.x, p.y, p.z, p.w};
    #pragma unroll
    for (int e = 0; e < 4; ++e)
      keyrow[(4 * s + e) * 64 + l] = mono1(av[e]);   // column 256s+4l+e
  }
  #pragma unroll
  for (int s = 0; s < 8; ++s) {
    const int j0 = 256 * s + 4 * l;
    float4 ra = *(const float4*)(randu + rowA + j0);   // cold
    float4 rb = *(const float4*)(randu + rowB + j0);   // cold
    float4 sc = *(const float4*)(scores + rowA + j0);  // L2-warm (P2)
    rndA |= (ra.x < thr ? 1u : 0u) << (4 * s + 0);
    rndA |= (ra.y < thr ? 1u : 0u) << (4 * s + 1);
    rndA |= (ra.z < thr ? 1u : 0u) << (4 * s + 2);
    rndA |= (ra.w < thr ? 1u : 0u) << (4 * s + 3);
    rndB |= (rb.x < thr ? 1u : 0u) << (4 * s + 0);
    rndB |= (rb.y < thr ? 1u : 0u) << (4 * s + 1);
    rndB |= (rb.z < thr ? 1u : 0u) << (4 * s + 2);
    rndB |= (rb.w < thr ? 1u : 0u) << (4 * s + 3);
    sbA[4 * s + 0] = __float_as_uint(sc.x);
    sbA[4 * s + 1] = __float_as_uint(sc.y);
    sbA[4 * s + 2] = __float_as_uint(sc.z);
    sbA[4 * s + 3] = __float_as_uint(sc.w);
  }
  __syncthreads();

  // ---- P3a: wave 0 reloads keys to regs, selects, publishes gq[l] ----
  if (w == 0) {
    unsigned gk[32];
    #pragma unroll
    for (int q = 0; q < 32; ++q)
      gk[q] = keyrow[q * 64 + l];            // stride-1: conflict-free
    unsigned Tg, kkg; bool c1g;
    resolve_T(gk, hist, l, Tg, kkg, c1g);
    unsigned gbits = select_bits(gk, Tg, kkg, c1g, l);
    const int lo = i - HALF_WIN;             // window [i-32, i+32)
    #pragma unroll
    for (int q = 0; q < 32; ++q) {
      const int j = 256 * (q >> 2) + 4 * l + (q & 3);
      gbits |= ((unsigned)(j - lo) < 64u ? 1u : 0u) << q;
    }
    gq[l] = gbits;
  }
  __syncthreads();
  const unsigned gql = gq[l];

  // ---- P3b head A: operands already in regs ----
  {
    const unsigned combined = gql | rndA;
    #pragma unroll
    for (int q = 0; q < 32; ++q) {
      const unsigned u = sbA[q];
      const unsigned m = (unsigned)((int)u >> 31) | 0x80000000u;
      const bool comb = ((combined >> q) & 1u) != 0u;
      sbA[q] = (comb ? u : (u & 0x80000000u)) ^ m;
    }
    unsigned T, kk; bool c1;
    resolve_T(sbA, h, l, T, kk, c1);
    unsigned bits = select_bits(sbA, T, kk, c1, l);
    #pragma unroll
    for (int s = 0; s < 8; ++s) {
      float v[4] __attribute__((aligned(16)));
      #pragma unroll
      for (int e = 0; e < 4; ++e)
        v[e] = ((bits >> (4 * s + e)) & 1u) ? 1.0f : 0.0f;
      *(float4*)(out + rowA + 256 * s + 4 * l) = *(const float4*)v;
    }
  }

  // ---- P3b head B: score re-read (L2-warm), build, select, write ----
  {
    unsigned sbB[32];
    #pragma unroll
    for (int s = 0; s < 8; ++s) {
      const int j0 = 256 * s + 4 * l;
      float4 sc = *(const float4*)(scores + rowB + j0);
      sbB[4 * s + 0] = __float_as_uint(sc.x);
      sbB[4 * s + 1] = __float_as_uint(sc.y);
      sbB[4 * s + 2] = __float_as_uint(sc.z);
      sbB[4 * s + 3] = __float_as_uint(sc.w);
    }
    const unsigned combined = gql | rndB;
    #pragma unroll
    for (int q = 0; q < 32; ++q) {
      const unsigned u = sbB[q];
      const unsigned m = (unsigned)((int)u >> 31) | 0x80000000u;
      const bool comb = ((combined >> q) & 1u) != 0u;
      sbB[q] = (comb ? u : (u & 0x80000000u)) ^ m;
    }
    unsigned T, kk; bool c1;
    resolve_T(sbB, h, l, T, kk, c1);
    unsigned bits = select_bits(sbB, T, kk, c1, l);
    #pragma unroll
    for (int s = 0; s < 8; ++s) {
      float v[4] __attribute__((aligned(16)));
      #pragma unroll
      for (int e = 0; e < 4; ++e)
        v[e] = ((bits >> (4 * s + e)) & 1u) ? 1.0f : 0.0f;
      *(float4*)(out + rowB + 256 * s + 4 * l) = *(const float4*)v;
    }
  }
}

extern "C" void kernel_launch(void* const* d_in, const int* in_sizes, int n_in,
                              void* d_out, int out_size, void* d_ws, size_t ws_size,
                              hipStream_t stream) {
  const float* scores = (const float*)d_in[0];
  const float* randu  = (const float*)d_in[1];
  float* out = (float*)d_out;
  (void)d_ws; (void)ws_size;
  k_fused<<<N_BATCH * S_LEN, 256, 0, stream>>>(scores, randu, out);
}

// Round 21
// 231.958 us; speedup vs baseline: 1.1140x; 1.1140x over previous
//
#include <hip/hip_runtime.h>
#include <cstdint>
#include <cstddef>

#define S_LEN   2048
#define N_HEADS 8
#define N_BATCH 2
#define TOPK    409      // int(2048 * (1.0 - 0.8)) in python double arithmetic
#define HALF_WIN 32
#define KEY_P0  0x80000000u   // mono(+0.0f)
#define KEY_N0  0x7FFFFFFFu   // mono(-0.0f)  (total order: -0 < +0)
#define HIST_STRIDE 260       // words; wave w's hist row starts at bank 4w

__device__ __forceinline__ unsigned mbcnt64(unsigned long long m) {
  return __builtin_amdgcn_mbcnt_hi((unsigned)(m >> 32),
         __builtin_amdgcn_mbcnt_lo((unsigned)m, 0u));
}

__device__ __forceinline__ unsigned mono1(float f) {
  unsigned u = __float_as_uint(f);
  return (u & 0x80000000u) ? ~u : (u | 0x80000000u);
}

// MSD radix select over the positive (key>+0) or negative (key<-0) subset.
// Wave-scope (no barriers). Keys in a register array.
__device__ __forceinline__ void radix_range(const unsigned (&keys)[32], unsigned kk0,
                                            bool pos, unsigned* h, int l,
                                            unsigned& T_ret, unsigned& kk_ret,
                                            bool& cnt1) {
  unsigned prefix = 0, done = 0, kk = kk0;
  unsigned T = 0;
  bool resolved = false;
  cnt1 = false;
  #pragma unroll
  for (int pass = 0; pass < 4; ++pass) {
    const int shift = 24 - 8 * pass;
    *(uint4*)&h[l * 4] = make_uint4(0, 0, 0, 0);
    __threadfence_block();
    #pragma unroll
    for (int q = 0; q < 32; ++q) {
      unsigned kj = keys[q];
      bool in = pos ? (kj > KEY_P0) : (kj < KEY_N0);
      if (in && (kj & done) == prefix)
        atomicAdd(&h[(kj >> shift) & 255u], 1u);
    }
    __threadfence_block();
    uint4 hv = *(const uint4*)&h[l * 4];
    unsigned s3 = hv.w;
    unsigned s2 = hv.z + s3;
    unsigned s1 = hv.y + s2;
    unsigned s0 = hv.x + s1;
    unsigned inc = s0;
    #pragma unroll
    for (int d = 1; d < 64; d <<= 1) {
      unsigned o = __shfl_down(inc, d);
      inc += (l + d < 64) ? o : 0u;
    }
    const unsigned tail = inc - s0;
    const unsigned ge[4] = {s0 + tail, s1 + tail, s2 + tail, s3 + tail};
    const unsigned gt[4] = {s1 + tail, s2 + tail, s3 + tail, tail};
    unsigned packed = 0;
    bool found = false;
    #pragma unroll
    for (int q = 0; q < 4; ++q) {
      if (gt[q] < kk && kk <= ge[q]) {
        packed = ((unsigned)(4 * l + q) << 24) | ((ge[q] - gt[q]) << 12) | (kk - gt[q]);
        found = true;
      }
    }
    unsigned long long bal = __ballot(found);
    int srcl = __ffsll((long long)bal) - 1;
    packed = __shfl(packed, srcl);
    const unsigned cnt = (packed >> 12) & 0xFFFu;
    kk = packed & 0xFFFu;
    prefix |= (packed >> 24) << shift;
    done |= 0xFFu << shift;
    if (cnt == 1u) {
      unsigned cand = 0;
      #pragma unroll
      for (int q = 0; q < 32; ++q) {
        unsigned kj = keys[q];
        bool in = pos ? (kj > KEY_P0) : (kj < KEY_N0);
        if (in && (kj & done) == prefix) cand = kj;
      }
      #pragma unroll
      for (int d = 1; d < 64; d <<= 1) cand |= __shfl_xor(cand, d);
      T = cand;                              // kk == 1 here
      resolved = true;
      cnt1 = true;
      break;
    }
  }
  if (!resolved) T = prefix;
  T_ret = T;
  kk_ret = kk;
}

// Resolve threshold T + tie-take count kk for top-TOPK of 2048 keys (32/lane).
// Order: positives > +0 > -0 > negatives; n0/n1 counted lazily.
__device__ __forceinline__ void resolve_T(const unsigned (&keys)[32], unsigned* h,
                                          int l, unsigned& T, unsigned& kk,
                                          bool& cnt1) {
  unsigned np = 0;
  #pragma unroll
  for (int q = 0; q < 32; ++q)
    np += (unsigned)__popcll(__ballot(keys[q] > KEY_P0));
  if (TOPK <= np) {
    radix_range(keys, TOPK, true, h, l, T, kk, cnt1);
  } else {
    unsigned n0 = 0, n1 = 0;
    #pragma unroll
    for (int q = 0; q < 32; ++q) {
      unsigned kj = keys[q];
      n0 += (unsigned)__popcll(__ballot(kj == KEY_P0));
      n1 += (unsigned)__popcll(__ballot(kj == KEY_N0));
    }
    if (TOPK <= np + n0)           { T = KEY_P0; kk = TOPK - np;      cnt1 = (n0 == 1); }
    else if (TOPK <= np + n0 + n1) { T = KEY_N0; kk = TOPK - np - n0; cnt1 = (n1 == 1); }
    else radix_range(keys, TOPK - np - n0 - n1, false, h, l, T, kk, cnt1);
  }
}

// Per-lane selection bits (bit q=4s+e <-> column j=256s+4l+e). Stable
// lowest-index-first tie handling; ballot-free fast path when cnt1.
__device__ __forceinline__ unsigned select_bits(const unsigned (&keys)[32],
                                                unsigned T, unsigned kk,
                                                bool cnt1, int l) {
  unsigned bits = 0;
  if (cnt1) {
    #pragma unroll
    for (int q = 0; q < 32; ++q)
      bits |= (keys[q] >= T ? 1u : 0u) << q;
    return bits;
  }
  unsigned S_tot = 0;
  #pragma unroll
  for (int s = 0; s < 8; ++s) {
    unsigned long long beq[4];
    unsigned pe[4];
    #pragma unroll
    for (int e = 0; e < 4; ++e) {
      beq[e] = __ballot(keys[4 * s + e] == T);
      pe[e] = (unsigned)__popcll(beq[e]);
    }
    const unsigned th = pe[0] + pe[1] + pe[2] + pe[3];
    if (S_tot + th <= kk) {
      #pragma unroll
      for (int e = 0; e < 4; ++e)
        bits |= (keys[4 * s + e] >= T ? 1u : 0u) << (4 * s + e);
    } else if (S_tot >= kk) {
      #pragma unroll
      for (int e = 0; e < 4; ++e)
        bits |= (keys[4 * s + e] > T ? 1u : 0u) << (4 * s + e);
    } else {                                 // boundary block (exactly one)
      unsigned mb[4], own[4];
      #pragma unroll
      for (int e = 0; e < 4; ++e) {
        mb[e]  = mbcnt64(beq[e]);
        own[e] = (unsigned)((beq[e] >> l) & 1ull);
      }
      const unsigned cross = S_tot + mb[0] + mb[1] + mb[2] + mb[3];
      unsigned run = 0;
      #pragma unroll
      for (int e = 0; e < 4; ++e) {
        unsigned kj = keys[4 * s + e];
        bool sel = (kj > T) || (kj == T && (cross + run) < kk);
        run += own[e];
        bits |= (sel ? 1u : 0u) << (4 * s + e);
      }
    }
    S_tot += th;
  }
  return bits;
}

// Fused kernel: block = (b,i), 256 threads = 4 waves, 2 heads per wave.
// = R19 (best, 200us) + rand-only prefetch: both heads' COLD rand rows are
// loaded during P2 (overlapping the sum's loads) and compressed to 2 regs
// before the barrier. R20 showed the compiler pins this kernel at 64 VGPRs
// and spills anything held across the barrier beyond one sb[32] set -- rnd
// bits are the only prefetch that fits. Score re-reads in P3b stay JIT
// (L2-warm from P2). P3b loop kept unroll-1 so head B's loads can't be
// hoisted (spill guard).
__global__ __launch_bounds__(256, 4) void k_fused(const float* __restrict__ scores,
                                                  const float* __restrict__ randu,
                                                  float* __restrict__ out) {
  __shared__ __align__(16) unsigned keyrow[S_LEN];         // 8 KB gmask keys
  __shared__ __align__(16) unsigned hist[4 * HIST_STRIDE]; // 4.2 KB
  __shared__ unsigned gq[64];                              // select words
  const int l = threadIdx.x & 63;          // lane
  const int w = threadIdx.x >> 6;          // wave 0..3
  const int bi = blockIdx.x;               // b * S + i
  const int b = bi >> 11;
  const int i = bi & 2047;
  const size_t gbase = (((size_t)(b * N_HEADS)) * S_LEN + i) * S_LEN; // head 0
  const float thr = (float)(1.0 - 0.8);    // 0x3E4CCCCD, JAX f32 demotion
  unsigned* const h = hist + (size_t)w * HIST_STRIDE;
  const size_t rowA = gbase + (size_t)(2 * w) * S_LEN * S_LEN;
  const size_t rowB = rowA + (size_t)S_LEN * S_LEN;

  // ---- P2: head-sum of own 512-col slice + rand prefetch (both heads) ----
  unsigned rndA = 0, rndB = 0;
  #pragma unroll
  for (int t = 0; t < 2; ++t) {
    const int s = 2 * w + t;               // 256-col chunk index
    const int c0 = 256 * s + 4 * l;
    float4 p = *(const float4*)(scores + gbase + c0);
    #pragma unroll
    for (int hh = 1; hh < N_HEADS; ++hh) {  // sequential head order
      float4 x = *(const float4*)(scores + gbase + (size_t)hh * S_LEN * S_LEN + c0);
      p.x += x.x; p.y += x.y; p.z += x.z; p.w += x.w;
    }
    const float av[4] = {p.x, p.y, p.z, p.w};
    #pragma unroll
    for (int e = 0; e < 4; ++e)
      keyrow[(4 * s + e) * 64 + l] = mono1(av[e]);   // column 256s+4l+e
  }
  #pragma unroll
  for (int s = 0; s < 8; ++s) {
    const int j0 = 256 * s + 4 * l;
    float4 ra = *(const float4*)(randu + rowA + j0);   // cold (HBM)
    float4 rb = *(const float4*)(randu + rowB + j0);   // cold (HBM)
    rndA |= (ra.x < thr ? 1u : 0u) << (4 * s + 0);
    rndA |= (ra.y < thr ? 1u : 0u) << (4 * s + 1);
    rndA |= (ra.z < thr ? 1u : 0u) << (4 * s + 2);
    rndA |= (ra.w < thr ? 1u : 0u) << (4 * s + 3);
    rndB |= (rb.x < thr ? 1u : 0u) << (4 * s + 0);
    rndB |= (rb.y < thr ? 1u : 0u) << (4 * s + 1);
    rndB |= (rb.z < thr ? 1u : 0u) << (4 * s + 2);
    rndB |= (rb.w < thr ? 1u : 0u) << (4 * s + 3);
  }
  __syncthreads();

  // ---- P3a: wave 0 reloads keys to regs, selects, publishes gq[l] ----
  if (w == 0) {
    unsigned gk[32];
    #pragma unroll
    for (int q = 0; q < 32; ++q)
      gk[q] = keyrow[q * 64 + l];            // stride-1: conflict-free
    unsigned Tg, kkg; bool c1g;
    resolve_T(gk, hist, l, Tg, kkg, c1g);
    unsigned gbits = select_bits(gk, Tg, kkg, c1g, l);
    const int lo = i - HALF_WIN;             // window [i-32, i+32)
    #pragma unroll
    for (int q = 0; q < 32; ++q) {
      const int j = 256 * (q >> 2) + 4 * l + (q & 3);
      gbits |= ((unsigned)(j - lo) < 64u ? 1u : 0u) << q;
    }
    gq[l] = gbits;
  }
  __syncthreads();
  const unsigned gql = gq[l];

  // ---- P3b: two heads, strictly sequential (register pressure control) ----
  #pragma unroll 1
  for (int t = 0; t < 2; ++t) {
    const size_t rowh = t ? rowB : rowA;
    const unsigned rnd = t ? rndB : rndA;
    unsigned sb[32];
    #pragma unroll
    for (int s = 0; s < 8; ++s) {
      const int j0 = 256 * s + 4 * l;
      float4 sc = *(const float4*)(scores + rowh + j0);  // L2-warm (P2)
      sb[4 * s + 0] = __float_as_uint(sc.x);
      sb[4 * s + 1] = __float_as_uint(sc.y);
      sb[4 * s + 2] = __float_as_uint(sc.z);
      sb[4 * s + 3] = __float_as_uint(sc.w);
    }
    const unsigned combined = gql | rnd;
    #pragma unroll
    for (int q = 0; q < 32; ++q) {
      const unsigned u = sb[q];
      const unsigned m = (unsigned)((int)u >> 31) | 0x80000000u;
      const bool comb = ((combined >> q) & 1u) != 0u;
      sb[q] = (comb ? u : (u & 0x80000000u)) ^ m;
    }
    unsigned T, kk; bool c1;
    resolve_T(sb, h, l, T, kk, c1);
    unsigned bits = select_bits(sb, T, kk, c1, l);
    #pragma unroll
    for (int s = 0; s < 8; ++s) {
      float v[4] __attribute__((aligned(16)));
      #pragma unroll
      for (int e = 0; e < 4; ++e)
        v[e] = ((bits >> (4 * s + e)) & 1u) ? 1.0f : 0.0f;
      *(float4*)(out + rowh + 256 * s + 4 * l) = *(const float4*)v;
    }
  }
}

extern "C" void kernel_launch(void* const* d_in, const int* in_sizes, int n_in,
                              void* d_out, int out_size, void* d_ws, size_t ws_size,
                              hipStream_t stream) {
  const float* scores = (const float*)d_in[0];
  const float* randu  = (const float*)d_in[1];
  float* out = (float*)d_out;
  (void)d_ws; (void)ws_size;
  k_fused<<<N_BATCH * S_LEN, 256, 0, stream>>>(scores, randu, out);
}

// Round 22
// 203.216 us; speedup vs baseline: 1.2716x; 1.1414x over previous
//
#include <hip/hip_runtime.h>
#include <cstdint>
#include <cstddef>

#define S_LEN   2048
#define N_HEADS 8
#define N_BATCH 2
#define TOPK    409      // int(2048 * (1.0 - 0.8)) in python double arithmetic
#define HALF_WIN 32
#define KEY_P0  0x80000000u   // mono(+0.0f)
#define KEY_N0  0x7FFFFFFFu   // mono(-0.0f)  (total order: -0 < +0)
#define HIST_STRIDE 260       // words; wave w's hist row starts at bank 4w

__device__ __forceinline__ unsigned mbcnt64(unsigned long long m) {
  return __builtin_amdgcn_mbcnt_hi((unsigned)(m >> 32),
         __builtin_amdgcn_mbcnt_lo((unsigned)m, 0u));
}

__device__ __forceinline__ unsigned mono1(float f) {
  unsigned u = __float_as_uint(f);
  return (u & 0x80000000u) ? ~u : (u | 0x80000000u);
}

// MSD radix select over the positive (key>+0) or negative (key<-0) subset.
// Wave-scope (no barriers). Keys in a register array.
__device__ __forceinline__ void radix_range(const unsigned (&keys)[32], unsigned kk0,
                                            bool pos, unsigned* h, int l,
                                            unsigned& T_ret, unsigned& kk_ret,
                                            bool& cnt1) {
  unsigned prefix = 0, done = 0, kk = kk0;
  unsigned T = 0;
  bool resolved = false;
  cnt1 = false;
  #pragma unroll
  for (int pass = 0; pass < 4; ++pass) {
    const int shift = 24 - 8 * pass;
    *(uint4*)&h[l * 4] = make_uint4(0, 0, 0, 0);
    __threadfence_block();
    #pragma unroll
    for (int q = 0; q < 32; ++q) {
      unsigned kj = keys[q];
      bool in = pos ? (kj > KEY_P0) : (kj < KEY_N0);
      if (in && (kj & done) == prefix)
        atomicAdd(&h[(kj >> shift) & 255u], 1u);
    }
    __threadfence_block();
    uint4 hv = *(const uint4*)&h[l * 4];
    unsigned s3 = hv.w;
    unsigned s2 = hv.z + s3;
    unsigned s1 = hv.y + s2;
    unsigned s0 = hv.x + s1;
    unsigned inc = s0;
    #pragma unroll
    for (int d = 1; d < 64; d <<= 1) {
      unsigned o = __shfl_down(inc, d);
      inc += (l + d < 64) ? o : 0u;
    }
    const unsigned tail = inc - s0;
    const unsigned ge[4] = {s0 + tail, s1 + tail, s2 + tail, s3 + tail};
    const unsigned gt[4] = {s1 + tail, s2 + tail, s3 + tail, tail};
    unsigned packed = 0;
    bool found = false;
    #pragma unroll
    for (int q = 0; q < 4; ++q) {
      if (gt[q] < kk && kk <= ge[q]) {
        packed = ((unsigned)(4 * l + q) << 24) | ((ge[q] - gt[q]) << 12) | (kk - gt[q]);
        found = true;
      }
    }
    unsigned long long bal = __ballot(found);
    int srcl = __ffsll((long long)bal) - 1;
    packed = __shfl(packed, srcl);
    const unsigned cnt = (packed >> 12) & 0xFFFu;
    kk = packed & 0xFFFu;
    prefix |= (packed >> 24) << shift;
    done |= 0xFFu << shift;
    if (cnt == 1u) {
      unsigned cand = 0;
      #pragma unroll
      for (int q = 0; q < 32; ++q) {
        unsigned kj = keys[q];
        bool in = pos ? (kj > KEY_P0) : (kj < KEY_N0);
        if (in && (kj & done) == prefix) cand = kj;
      }
      #pragma unroll
      for (int d = 1; d < 64; d <<= 1) cand |= __shfl_xor(cand, d);
      T = cand;                              // kk == 1 here
      resolved = true;
      cnt1 = true;
      break;
    }
  }
  if (!resolved) T = prefix;
  T_ret = T;
  kk_ret = kk;
}

// Resolve threshold T + tie-take count kk for top-TOPK of 2048 keys (32/lane).
// Order: positives > +0 > -0 > negatives; n0/n1 counted lazily.
__device__ __forceinline__ void resolve_T(const unsigned (&keys)[32], unsigned* h,
                                          int l, unsigned& T, unsigned& kk,
                                          bool& cnt1) {
  unsigned np = 0;
  #pragma unroll
  for (int q = 0; q < 32; ++q)
    np += (unsigned)__popcll(__ballot(keys[q] > KEY_P0));
  if (TOPK <= np) {
    radix_range(keys, TOPK, true, h, l, T, kk, cnt1);
  } else {
    unsigned n0 = 0, n1 = 0;
    #pragma unroll
    for (int q = 0; q < 32; ++q) {
      unsigned kj = keys[q];
      n0 += (unsigned)__popcll(__ballot(kj == KEY_P0));
      n1 += (unsigned)__popcll(__ballot(kj == KEY_N0));
    }
    if (TOPK <= np + n0)           { T = KEY_P0; kk = TOPK - np;      cnt1 = (n0 == 1); }
    else if (TOPK <= np + n0 + n1) { T = KEY_N0; kk = TOPK - np - n0; cnt1 = (n1 == 1); }
    else radix_range(keys, TOPK - np - n0 - n1, false, h, l, T, kk, cnt1);
  }
}

// Per-lane selection bits (bit q=4s+e <-> column j=256s+4l+e). Stable
// lowest-index-first tie handling; ballot-free fast path when cnt1.
__device__ __forceinline__ unsigned select_bits(const unsigned (&keys)[32],
                                                unsigned T, unsigned kk,
                                                bool cnt1, int l) {
  unsigned bits = 0;
  if (cnt1) {
    #pragma unroll
    for (int q = 0; q < 32; ++q)
      bits |= (keys[q] >= T ? 1u : 0u) << q;
    return bits;
  }
  unsigned S_tot = 0;
  #pragma unroll
  for (int s = 0; s < 8; ++s) {
    unsigned long long beq[4];
    unsigned pe[4];
    #pragma unroll
    for (int e = 0; e < 4; ++e) {
      beq[e] = __ballot(keys[4 * s + e] == T);
      pe[e] = (unsigned)__popcll(beq[e]);
    }
    const unsigned th = pe[0] + pe[1] + pe[2] + pe[3];
    if (S_tot + th <= kk) {
      #pragma unroll
      for (int e = 0; e < 4; ++e)
        bits |= (keys[4 * s + e] >= T ? 1u : 0u) << (4 * s + e);
    } else if (S_tot >= kk) {
      #pragma unroll
      for (int e = 0; e < 4; ++e)
        bits |= (keys[4 * s + e] > T ? 1u : 0u) << (4 * s + e);
    } else {                                 // boundary block (exactly one)
      unsigned mb[4], own[4];
      #pragma unroll
      for (int e = 0; e < 4; ++e) {
        mb[e]  = mbcnt64(beq[e]);
        own[e] = (unsigned)((beq[e] >> l) & 1ull);
      }
      const unsigned cross = S_tot + mb[0] + mb[1] + mb[2] + mb[3];
      unsigned run = 0;
      #pragma unroll
      for (int e = 0; e < 4; ++e) {
        unsigned kj = keys[4 * s + e];
        bool sel = (kj > T) || (kj == T && (cross + run) < kk);
        run += own[e];
        bits |= (sel ? 1u : 0u) << (4 * s + e);
      }
    }
    S_tot += th;
  }
  return bits;
}

// Fused kernel: block = (b,i), 256 threads = 4 waves, 2 heads per wave.
// = R19 (best) with the gmask select DISTRIBUTED: every wave redundantly
// reloads the 2048 gmask keys (stride-1 transposed keyrow: conflict-free;
// cross-wave same-address reads broadcast) and runs the register select on
// its own bank-staggered hist row -> identical gbits everywhere. Deletes
// the gq round-trip, the second barrier, and all wave-0-serial idle time;
// ONE barrier total. At select time the live set is gk[32]+temps (dies
// before P3b's sb[32]) -> fits the compiler's 64-VGPR pin, no spill.
__global__ __launch_bounds__(256, 4) void k_fused(const float* __restrict__ scores,
                                                  const float* __restrict__ randu,
                                                  float* __restrict__ out) {
  __shared__ __align__(16) unsigned keyrow[S_LEN];         // 8 KB gmask keys
  __shared__ __align__(16) unsigned hist[4 * HIST_STRIDE]; // 4.2 KB
  const int l = threadIdx.x & 63;          // lane
  const int w = threadIdx.x >> 6;          // wave 0..3
  const int bi = blockIdx.x;               // b * S + i
  const int b = bi >> 11;
  const int i = bi & 2047;
  const size_t gbase = (((size_t)(b * N_HEADS)) * S_LEN + i) * S_LEN; // head 0
  const float thr = (float)(1.0 - 0.8);    // 0x3E4CCCCD, JAX f32 demotion
  unsigned* const h = hist + (size_t)w * HIST_STRIDE;
  const size_t rowA = gbase + (size_t)(2 * w) * S_LEN * S_LEN;
  const size_t rowB = rowA + (size_t)S_LEN * S_LEN;

  // ---- P2: head-sum of own 512-col slice (two 256-col chunks) ----
  #pragma unroll
  for (int t = 0; t < 2; ++t) {
    const int s = 2 * w + t;               // 256-col chunk index
    const int c0 = 256 * s + 4 * l;
    float4 p = *(const float4*)(scores + gbase + c0);
    #pragma unroll
    for (int hh = 1; hh < N_HEADS; ++hh) {  // sequential head order
      float4 x = *(const float4*)(scores + gbase + (size_t)hh * S_LEN * S_LEN + c0);
      p.x += x.x; p.y += x.y; p.z += x.z; p.w += x.w;
    }
    const float av[4] = {p.x, p.y, p.z, p.w};
    #pragma unroll
    for (int e = 0; e < 4; ++e)
      keyrow[(4 * s + e) * 64 + l] = mono1(av[e]);   // column 256s+4l+e
  }
  __syncthreads();                         // the ONLY barrier

  // ---- P3a: EVERY wave computes the gmask select (identical results) ----
  unsigned gql;
  {
    unsigned gk[32];
    #pragma unroll
    for (int q = 0; q < 32; ++q)
      gk[q] = keyrow[q * 64 + l];            // stride-1: conflict-free
    unsigned Tg, kkg; bool c1g;
    resolve_T(gk, h, l, Tg, kkg, c1g);
    unsigned gbits = select_bits(gk, Tg, kkg, c1g, l);
    const int lo = i - HALF_WIN;             // window [i-32, i+32)
    #pragma unroll
    for (int q = 0; q < 32; ++q) {
      const int j = 256 * (q >> 2) + 4 * l + (q & 3);
      gbits |= ((unsigned)(j - lo) < 64u ? 1u : 0u) << q;
    }
    gql = gbits;
  }

  // ---- P3b: two heads, strictly sequential (register pressure control) ----
  #pragma unroll 1
  for (int t = 0; t < 2; ++t) {
    const size_t rowh = t ? rowB : rowA;
    unsigned sb[32];
    unsigned rnd = 0;
    #pragma unroll
    for (int s = 0; s < 8; ++s) {
      const int j0 = 256 * s + 4 * l;
      float4 sc = *(const float4*)(scores + rowh + j0);  // L2-warm (P2)
      float4 ru = *(const float4*)(randu + rowh + j0);   // cold (only read)
      sb[4 * s + 0] = __float_as_uint(sc.x);
      sb[4 * s + 1] = __float_as_uint(sc.y);
      sb[4 * s + 2] = __float_as_uint(sc.z);
      sb[4 * s + 3] = __float_as_uint(sc.w);
      rnd |= (ru.x < thr ? 1u : 0u) << (4 * s + 0);
      rnd |= (ru.y < thr ? 1u : 0u) << (4 * s + 1);
      rnd |= (ru.z < thr ? 1u : 0u) << (4 * s + 2);
      rnd |= (ru.w < thr ? 1u : 0u) << (4 * s + 3);
    }
    const unsigned combined = gql | rnd;
    #pragma unroll
    for (int q = 0; q < 32; ++q) {
      const unsigned u = sb[q];
      const unsigned m = (unsigned)((int)u >> 31) | 0x80000000u;
      const bool comb = ((combined >> q) & 1u) != 0u;
      sb[q] = (comb ? u : (u & 0x80000000u)) ^ m;
    }
    unsigned T, kk; bool c1;
    resolve_T(sb, h, l, T, kk, c1);
    unsigned bits = select_bits(sb, T, kk, c1, l);
    #pragma unroll
    for (int s = 0; s < 8; ++s) {
      float v[4] __attribute__((aligned(16)));
      #pragma unroll
      for (int e = 0; e < 4; ++e)
        v[e] = ((bits >> (4 * s + e)) & 1u) ? 1.0f : 0.0f;
      *(float4*)(out + rowh + 256 * s + 4 * l) = *(const float4*)v;
    }
  }
}

extern "C" void kernel_launch(void* const* d_in, const int* in_sizes, int n_in,
                              void* d_out, int out_size, void* d_ws, size_t ws_size,
                              hipStream_t stream) {
  const float* scores = (const float*)d_in[0];
  const float* randu  = (const float*)d_in[1];
  float* out = (float*)d_out;
  (void)d_ws; (void)ws_size;
  k_fused<<<N_BATCH * S_LEN, 256, 0, stream>>>(scores, randu, out);
}

// Round 23
// 184.308 us; speedup vs baseline: 1.4020x; 1.1026x over previous
//
#include <hip/hip_runtime.h>
#include <cstdint>
#include <cstddef>

#define S_LEN   2048
#define N_HEADS 8
#define N_BATCH 2
#define TOPK    409      // int(2048 * (1.0 - 0.8)) in python double arithmetic
#define HALF_WIN 32
#define KEY_P0  0x80000000u   // mono(+0.0f)
#define KEY_N0  0x7FFFFFFFu   // mono(-0.0f)  (total order: -0 < +0)
#define HIST_STRIDE 260       // words; wave w's hist row starts at bank 4w

__device__ __forceinline__ unsigned mbcnt64(unsigned long long m) {
  return __builtin_amdgcn_mbcnt_hi((unsigned)(m >> 32),
         __builtin_amdgcn_mbcnt_lo((unsigned)m, 0u));
}

__device__ __forceinline__ unsigned mono1(float f) {
  unsigned u = __float_as_uint(f);
  return (u & 0x80000000u) ? ~u : (u | 0x80000000u);
}

// MSD radix select over the positive (key>+0) or negative (key<-0) subset.
// Wave-scope (no barriers). Keys in a register array.
__device__ __forceinline__ void radix_range(const unsigned (&keys)[32], unsigned kk0,
                                            bool pos, unsigned* h, int l,
                                            unsigned& T_ret, unsigned& kk_ret,
                                            bool& cnt1) {
  unsigned prefix = 0, done = 0, kk = kk0;
  unsigned T = 0;
  bool resolved = false;
  cnt1 = false;
  #pragma unroll
  for (int pass = 0; pass < 4; ++pass) {
    const int shift = 24 - 8 * pass;
    *(uint4*)&h[l * 4] = make_uint4(0, 0, 0, 0);
    __threadfence_block();
    #pragma unroll
    for (int q = 0; q < 32; ++q) {
      unsigned kj = keys[q];
      bool in = pos ? (kj > KEY_P0) : (kj < KEY_N0);
      if (in && (kj & done) == prefix)
        atomicAdd(&h[(kj >> shift) & 255u], 1u);
    }
    __threadfence_block();
    uint4 hv = *(const uint4*)&h[l * 4];
    unsigned s3 = hv.w;
    unsigned s2 = hv.z + s3;
    unsigned s1 = hv.y + s2;
    unsigned s0 = hv.x + s1;
    unsigned inc = s0;
    #pragma unroll
    for (int d = 1; d < 64; d <<= 1) {
      unsigned o = __shfl_down(inc, d);
      inc += (l + d < 64) ? o : 0u;
    }
    const unsigned tail = inc - s0;
    const unsigned ge[4] = {s0 + tail, s1 + tail, s2 + tail, s3 + tail};
    const unsigned gt[4] = {s1 + tail, s2 + tail, s3 + tail, tail};
    unsigned packed = 0;
    bool found = false;
    #pragma unroll
    for (int q = 0; q < 4; ++q) {
      if (gt[q] < kk && kk <= ge[q]) {
        packed = ((unsigned)(4 * l + q) << 24) | ((ge[q] - gt[q]) << 12) | (kk - gt[q]);
        found = true;
      }
    }
    unsigned long long bal = __ballot(found);
    int srcl = __ffsll((long long)bal) - 1;
    packed = __shfl(packed, srcl);
    const unsigned cnt = (packed >> 12) & 0xFFFu;
    kk = packed & 0xFFFu;
    prefix |= (packed >> 24) << shift;
    done |= 0xFFu << shift;
    if (cnt == 1u) {
      unsigned cand = 0;
      #pragma unroll
      for (int q = 0; q < 32; ++q) {
        unsigned kj = keys[q];
        bool in = pos ? (kj > KEY_P0) : (kj < KEY_N0);
        if (in && (kj & done) == prefix) cand = kj;
      }
      #pragma unroll
      for (int d = 1; d < 64; d <<= 1) cand |= __shfl_xor(cand, d);
      T = cand;                              // kk == 1 here
      resolved = true;
      cnt1 = true;
      break;
    }
  }
  if (!resolved) T = prefix;
  T_ret = T;
  kk_ret = kk;
}

// Resolve threshold T + tie-take count kk for top-TOPK of 2048 keys (32/lane).
// Order: positives > +0 > -0 > negatives; n0/n1 counted lazily.
__device__ __forceinline__ void resolve_T(const unsigned (&keys)[32], unsigned* h,
                                          int l, unsigned& T, unsigned& kk,
                                          bool& cnt1) {
  unsigned np = 0;
  #pragma unroll
  for (int q = 0; q < 32; ++q)
    np += (unsigned)__popcll(__ballot(keys[q] > KEY_P0));
  if (TOPK <= np) {
    radix_range(keys, TOPK, true, h, l, T, kk, cnt1);
  } else {
    unsigned n0 = 0, n1 = 0;
    #pragma unroll
    for (int q = 0; q < 32; ++q) {
      unsigned kj = keys[q];
      n0 += (unsigned)__popcll(__ballot(kj == KEY_P0));
      n1 += (unsigned)__popcll(__ballot(kj == KEY_N0));
    }
    if (TOPK <= np + n0)           { T = KEY_P0; kk = TOPK - np;      cnt1 = (n0 == 1); }
    else if (TOPK <= np + n0 + n1) { T = KEY_N0; kk = TOPK - np - n0; cnt1 = (n1 == 1); }
    else radix_range(keys, TOPK - np - n0 - n1, false, h, l, T, kk, cnt1);
  }
}

// Per-lane selection bits (bit q=4s+e <-> column j=256s+4l+e). Stable
// lowest-index-first tie handling; ballot-free fast path when cnt1.
__device__ __forceinline__ unsigned select_bits(const unsigned (&keys)[32],
                                                unsigned T, unsigned kk,
                                                bool cnt1, int l) {
  unsigned bits = 0;
  if (cnt1) {
    #pragma unroll
    for (int q = 0; q < 32; ++q)
      bits |= (keys[q] >= T ? 1u : 0u) << q;
    return bits;
  }
  unsigned S_tot = 0;
  #pragma unroll
  for (int s = 0; s < 8; ++s) {
    unsigned long long beq[4];
    unsigned pe[4];
    #pragma unroll
    for (int e = 0; e < 4; ++e) {
      beq[e] = __ballot(keys[4 * s + e] == T);
      pe[e] = (unsigned)__popcll(beq[e]);
    }
    const unsigned th = pe[0] + pe[1] + pe[2] + pe[3];
    if (S_tot + th <= kk) {
      #pragma unroll
      for (int e = 0; e < 4; ++e)
        bits |= (keys[4 * s + e] >= T ? 1u : 0u) << (4 * s + e);
    } else if (S_tot >= kk) {
      #pragma unroll
      for (int e = 0; e < 4; ++e)
        bits |= (keys[4 * s + e] > T ? 1u : 0u) << (4 * s + e);
    } else {                                 // boundary block (exactly one)
      unsigned mb[4], own[4];
      #pragma unroll
      for (int e = 0; e < 4; ++e) {
        mb[e]  = mbcnt64(beq[e]);
        own[e] = (unsigned)((beq[e] >> l) & 1ull);
      }
      const unsigned cross = S_tot + mb[0] + mb[1] + mb[2] + mb[3];
      unsigned run = 0;
      #pragma unroll
      for (int e = 0; e < 4; ++e) {
        unsigned kj = keys[4 * s + e];
        bool sel = (kj > T) || (kj == T && (cross + run) < kk);
        run += own[e];
        bits |= (sel ? 1u : 0u) << (4 * s + e);
      }
    }
    S_tot += th;
  }
  return bits;
}

// Fused kernel: block = (b,i), 256 threads = 4 waves, 2 heads per wave.
// = R19 (best, 200us) with wave-DIVERGENT overlap: after keyrow is ready,
// wave 0 runs the gmask select (publishes gq) while waves 1-3 preload their
// head-A score/rand rows. Spill-safe (vs R20): no program point holds BOTH
// gk[32] and sbA[32] -- wave 0 skips the preload and loads head A JIT after
// the barrier. Head B stays JIT for all waves. Compiler pins this kernel at
// 64 VGPRs; each path's peak live set is one 32-word array + temps.
__global__ __launch_bounds__(256, 4) void k_fused(const float* __restrict__ scores,
                                                  const float* __restrict__ randu,
                                                  float* __restrict__ out) {
  __shared__ __align__(16) unsigned keyrow[S_LEN];         // 8 KB gmask keys
  __shared__ __align__(16) unsigned hist[4 * HIST_STRIDE]; // 4.2 KB
  __shared__ unsigned gq[64];                              // select words
  const int l = threadIdx.x & 63;          // lane
  const int w = threadIdx.x >> 6;          // wave 0..3
  const int bi = blockIdx.x;               // b * S + i
  const int b = bi >> 11;
  const int i = bi & 2047;
  const size_t gbase = (((size_t)(b * N_HEADS)) * S_LEN + i) * S_LEN; // head 0
  const float thr = (float)(1.0 - 0.8);    // 0x3E4CCCCD, JAX f32 demotion
  unsigned* const h = hist + (size_t)w * HIST_STRIDE;
  const size_t rowA = gbase + (size_t)(2 * w) * S_LEN * S_LEN;
  const size_t rowB = rowA + (size_t)S_LEN * S_LEN;

  // ---- P2: head-sum of own 512-col slice (two 256-col chunks) ----
  #pragma unroll
  for (int t = 0; t < 2; ++t) {
    const int s = 2 * w + t;               // 256-col chunk index
    const int c0 = 256 * s + 4 * l;
    float4 p = *(const float4*)(scores + gbase + c0);
    #pragma unroll
    for (int hh = 1; hh < N_HEADS; ++hh) {  // sequential head order
      float4 x = *(const float4*)(scores + gbase + (size_t)hh * S_LEN * S_LEN + c0);
      p.x += x.x; p.y += x.y; p.z += x.z; p.w += x.w;
    }
    const float av[4] = {p.x, p.y, p.z, p.w};
    #pragma unroll
    for (int e = 0; e < 4; ++e)
      keyrow[(4 * s + e) * 64 + l] = mono1(av[e]);   // column 256s+4l+e
  }
  __syncthreads();

  // ---- Divergent: wave 0 gmask-selects; waves 1-3 preload head A ----
  unsigned sbA[32];
  unsigned rndA = 0;
  if (w == 0) {
    unsigned gk[32];
    #pragma unroll
    for (int q = 0; q < 32; ++q)
      gk[q] = keyrow[q * 64 + l];            // stride-1: conflict-free
    unsigned Tg, kkg; bool c1g;
    resolve_T(gk, hist, l, Tg, kkg, c1g);
    unsigned gbits = select_bits(gk, Tg, kkg, c1g, l);
    const int lo = i - HALF_WIN;             // window [i-32, i+32)
    #pragma unroll
    for (int q = 0; q < 32; ++q) {
      const int j = 256 * (q >> 2) + 4 * l + (q & 3);
      gbits |= ((unsigned)(j - lo) < 64u ? 1u : 0u) << q;
    }
    gq[l] = gbits;
  } else {
    #pragma unroll
    for (int s = 0; s < 8; ++s) {
      const int j0 = 256 * s + 4 * l;
      float4 sc = *(const float4*)(scores + rowA + j0);  // L2-warm (P2)
      float4 ru = *(const float4*)(randu + rowA + j0);   // cold (HBM)
      sbA[4 * s + 0] = __float_as_uint(sc.x);
      sbA[4 * s + 1] = __float_as_uint(sc.y);
      sbA[4 * s + 2] = __float_as_uint(sc.z);
      sbA[4 * s + 3] = __float_as_uint(sc.w);
      rndA |= (ru.x < thr ? 1u : 0u) << (4 * s + 0);
      rndA |= (ru.y < thr ? 1u : 0u) << (4 * s + 1);
      rndA |= (ru.z < thr ? 1u : 0u) << (4 * s + 2);
      rndA |= (ru.w < thr ? 1u : 0u) << (4 * s + 3);
    }
  }
  __syncthreads();
  const unsigned gql = gq[l];

  // ---- P3b head A: wave 0 loads JIT; others have operands in regs ----
  if (w == 0) {
    #pragma unroll
    for (int s = 0; s < 8; ++s) {
      const int j0 = 256 * s + 4 * l;
      float4 sc = *(const float4*)(scores + rowA + j0);
      float4 ru = *(const float4*)(randu + rowA + j0);
      sbA[4 * s + 0] = __float_as_uint(sc.x);
      sbA[4 * s + 1] = __float_as_uint(sc.y);
      sbA[4 * s + 2] = __float_as_uint(sc.z);
      sbA[4 * s + 3] = __float_as_uint(sc.w);
      rndA |= (ru.x < thr ? 1u : 0u) << (4 * s + 0);
      rndA |= (ru.y < thr ? 1u : 0u) << (4 * s + 1);
      rndA |= (ru.z < thr ? 1u : 0u) << (4 * s + 2);
      rndA |= (ru.w < thr ? 1u : 0u) << (4 * s + 3);
    }
  }
  {
    const unsigned combined = gql | rndA;
    #pragma unroll
    for (int q = 0; q < 32; ++q) {
      const unsigned u = sbA[q];
      const unsigned m = (unsigned)((int)u >> 31) | 0x80000000u;
      const bool comb = ((combined >> q) & 1u) != 0u;
      sbA[q] = (comb ? u : (u & 0x80000000u)) ^ m;
    }
    unsigned T, kk; bool c1;
    resolve_T(sbA, h, l, T, kk, c1);
    unsigned bits = select_bits(sbA, T, kk, c1, l);
    #pragma unroll
    for (int s = 0; s < 8; ++s) {
      float v[4] __attribute__((aligned(16)));
      #pragma unroll
      for (int e = 0; e < 4; ++e)
        v[e] = ((bits >> (4 * s + e)) & 1u) ? 1.0f : 0.0f;
      *(float4*)(out + rowA + 256 * s + 4 * l) = *(const float4*)v;
    }
  }

  // ---- P3b head B: JIT loads (score L2-warm, rand cold), select, write ----
  {
    unsigned sbB[32];
    unsigned rndB = 0;
    #pragma unroll
    for (int s = 0; s < 8; ++s) {
      const int j0 = 256 * s + 4 * l;
      float4 sc = *(const float4*)(scores + rowB + j0);
      float4 ru = *(const float4*)(randu + rowB + j0);
      sbB[4 * s + 0] = __float_as_uint(sc.x);
      sbB[4 * s + 1] = __float_as_uint(sc.y);
      sbB[4 * s + 2] = __float_as_uint(sc.z);
      sbB[4 * s + 3] = __float_as_uint(sc.w);
      rndB |= (ru.x < thr ? 1u : 0u) << (4 * s + 0);
      rndB |= (ru.y < thr ? 1u : 0u) << (4 * s + 1);
      rndB |= (ru.z < thr ? 1u : 0u) << (4 * s + 2);
      rndB |= (ru.w < thr ? 1u : 0u) << (4 * s + 3);
    }
    const unsigned combined = gql | rndB;
    #pragma unroll
    for (int q = 0; q < 32; ++q) {
      const unsigned u = sbB[q];
      const unsigned m = (unsigned)((int)u >> 31) | 0x80000000u;
      const bool comb = ((combined >> q) & 1u) != 0u;
      sbB[q] = (comb ? u : (u & 0x80000000u)) ^ m;
    }
    unsigned T, kk; bool c1;
    resolve_T(sbB, h, l, T, kk, c1);
    unsigned bits = select_bits(sbB, T, kk, c1, l);
    #pragma unroll
    for (int s = 0; s < 8; ++s) {
      float v[4] __attribute__((aligned(16)));
      #pragma unroll
      for (int e = 0; e < 4; ++e)
        v[e] = ((bits >> (4 * s + e)) & 1u) ? 1.0f : 0.0f;
      *(float4*)(out + rowB + 256 * s + 4 * l) = *(const float4*)v;
    }
  }
}

extern "C" void kernel_launch(void* const* d_in, const int* in_sizes, int n_in,
                              void* d_out, int out_size, void* d_ws, size_t ws_size,
                              hipStream_t stream) {
  const float* scores = (const float*)d_in[0];
  const float* randu  = (const float*)d_in[1];
  float* out = (float*)d_out;
  (void)d_ws; (void)ws_size;
  k_fused<<<N_BATCH * S_LEN, 256, 0, stream>>>(scores, randu, out);
}